// Round 11
// baseline (93.287 us; speedup 1.0000x reference)
//
#include <hip/hip_runtime.h>

typedef __attribute__((ext_vector_type(8))) short short8;
typedef __attribute__((ext_vector_type(4))) float f32x4;

#define T_DIM 4096
#define C_DIM 128
#define U_DIM 256
#define BM 128
#define NROWS 130   // BM + 2 halo rows
#define LDK 136     // padded LDS row stride (bf16 elems)

__device__ __forceinline__ unsigned short f2bf(float f) {
    unsigned int u = __float_as_uint(f);
    u += 0x7FFFu + ((u >> 16) & 1u);   // round-to-nearest-even
    return (unsigned short)(u >> 16);
}

// Pre-pack w into MFMA fragment order: wfrag[ks][nt][lane][8] bf16,
// where k = ks*32 + (lane>>4)*8 + j, u = nt*16 + (lane&15).
__global__ void prep_kernel(const float* __restrict__ w,
                            const float* __restrict__ b,
                            const float* __restrict__ p,
                            const float* __restrict__ q,
                            unsigned short* __restrict__ wfrag,
                            float* __restrict__ winv,
                            float* __restrict__ p2,
                            float* __restrict__ bc) {
    if (blockIdx.x < 48) {
        int idx = blockIdx.x * 256 + threadIdx.x;   // 0..12287 lane-frags
        int l  = idx & 63;
        int nt = (idx >> 6) & 15;
        int ks = idx >> 10;                         // 0..11
        int n  = nt * 16 + (l & 15);
        int k0 = ks * 32 + ((l >> 4) << 3);
        #pragma unroll
        for (int j = 0; j < 8; ++j) {
            wfrag[(size_t)idx * 8 + j] = f2bf(w[(k0 + j) * U_DIM + n]);
        }
    } else {
        int u = threadIdx.x;                        // 0..255
        float ss = 0.f;
        for (int k = 0; k < 3 * C_DIM; ++k) {
            float v = w[k * U_DIM + u];
            ss += v * v;
        }
        float q2 = q[0] * q[0];
        winv[u] = 1.0f / (sqrtf(fmaxf(ss, 1e-12f)) + q2);
        float pv = p[u];
        p2[u] = pv * pv;
        bc[u] = b[u];
    }
}

__global__ __launch_bounds__(512, 4) void cossim_main(
        const float* __restrict__ inp,
        const unsigned short* __restrict__ wfrag,
        const float* __restrict__ winv,
        const float* __restrict__ p2g,
        const float* __restrict__ bg,
        const float* __restrict__ qg,
        float* __restrict__ out,
        int reps, float iscale) {
    __shared__ unsigned short inp_s[NROWS][LDK];
    __shared__ float ss_s[NROWS];
    __shared__ float xninv_s[BM];

    const int tid  = threadIdx.x;
    const int bidx = blockIdx.x;
    const int bb   = bidx >> 5;          // batch index (32 tiles per batch)
    const int t0   = (bidx & 31) * BM;   // tile start within batch

    // ---- Stage 130 input rows (t0-1 .. t0+128) as bf16; f32 sumsq per row ----
    {
        const int r0 = tid >> 5;         // 0..15
        const int lc = (tid & 31) * 4;   // float column
        float4 v[9];
        #pragma unroll
        for (int i = 0; i < 9; ++i) {
            int r = r0 + i * 16;
            int t = t0 + r - 1;
            float4 val = make_float4(0.f, 0.f, 0.f, 0.f);
            if (r < NROWS && t >= 0 && t < T_DIM) {
                val = *(const float4*)(inp + ((size_t)bb * T_DIM + t) * C_DIM + lc);
            }
            v[i] = val;
        }
        #pragma unroll
        for (int i = 0; i < 9; ++i) {
            int r = r0 + i * 16;
            if (r < NROWS) {
                float4 val = v[i];
                float part = val.x * val.x + val.y * val.y + val.z * val.z + val.w * val.w;
                #pragma unroll
                for (int o = 16; o > 0; o >>= 1) part += __shfl_xor(part, o, 32);
                if ((tid & 31) == 0) ss_s[r] = part;
                ushort4 sv;
                sv.x = f2bf(val.x); sv.y = f2bf(val.y);
                sv.z = f2bf(val.z); sv.w = f2bf(val.w);
                *(ushort4*)(&inp_s[r][lc]) = sv;
            }
        }
    }
    __syncthreads();
    if (tid < BM) {
        float s3 = ss_s[tid] + ss_s[tid + 1] + ss_s[tid + 2];
        float q2 = qg[0] * qg[0];
        xninv_s[tid] = 1.0f / (sqrtf(fmaxf(s3, 1e-12f)) + q2);
    }
    __syncthreads();

    // ---- MFMA: 8 waves as 2(T) x 4(U); each wave 64(t) x 64(u) ----
    const int wid = tid >> 6;
    const int l   = tid & 63;
    const int tw  = wid >> 2;        // 0..1 (t 64-row half)
    const int uw  = wid & 3;         // 0..3 (u 64-col quarter)
    const int l15 = l & 15;
    const int lg  = l >> 4;          // 0..3

    f32x4 acc[4][4];                 // [tf][uf]
    #pragma unroll
    for (int tf = 0; tf < 4; ++tf)
        #pragma unroll
        for (int uf = 0; uf < 4; ++uf)
            acc[tf][uf] = (f32x4){0.f, 0.f, 0.f, 0.f};

    const short8* wf = (const short8*)wfrag;

    // ---- PROBE: run the K-loop `reps` times (host passes 2), accumulating.
    // Laundered offsets (fresh per rep) prevent load CSE across reps, so each
    // rep re-issues all 48 wv L2 loads + 48 ds_reads. Exact 1/reps is folded
    // into xi below (iscale = 0.5f, power of two -> bit-identical output).
    #pragma unroll 1
    for (int rep = 0; rep < reps; ++rep) {
        int xoff = 0;
        size_t woff = 0;
        asm volatile("" : "+v"(xoff));
        asm volatile("" : "+v"(woff));
        #pragma unroll
        for (int ks = 0; ks < 12; ++ks) {
            const int tap = ks >> 2;                    // which of the 3 taps
            const int c0  = (ks & 3) * 32 + lg * 8;     // bf16 column within tap
            short8 xv[4], wv[4];
            #pragma unroll
            for (int tf = 0; tf < 4; ++tf) {
                int row = tw * 64 + tf * 16 + l15 + tap;   // halo-shifted LDS row
                xv[tf] = *(const short8*)(&inp_s[row][c0 + xoff]);
            }
            #pragma unroll
            for (int uf = 0; uf < 4; ++uf) {
                wv[uf] = wf[(size_t)(ks * 16 + uw * 4 + uf) * 64 + l + woff];
            }
            #pragma unroll
            for (int tf = 0; tf < 4; ++tf)
                #pragma unroll
                for (int uf = 0; uf < 4; ++uf)
                    acc[tf][uf] = __builtin_amdgcn_mfma_f32_16x16x32_bf16(
                        wv[uf], xv[tf], acc[tf][uf], 0, 0, 0);
        }
    }

    // ---- Epilogue: compact (no libm powf); xi carries iscale = 1/reps.
    #pragma unroll
    for (int tf = 0; tf < 4; ++tf) {
        int trow = tw * 64 + tf * 16 + l15;
        float xi = xninv_s[trow] * iscale;
        float* orow = out + ((size_t)bb * T_DIM + t0 + trow) * U_DIM;
        #pragma unroll
        for (int uf = 0; uf < 4; ++uf) {
            int uc = uw * 64 + uf * 16 + lg * 4;
            f32x4 wiv = *(const f32x4*)(winv + uc);
            f32x4 ppv = *(const f32x4*)(p2g + uc);
            f32x4 bbv = *(const f32x4*)(bg + uc);
            f32x4 r;
            #pragma unroll
            for (int j = 0; j < 4; ++j) {
                float raw = acc[tf][uf][j];
                float y   = raw * xi * wiv[j];
                float ay  = fabsf(y) + 1e-12f;
                float pw  = ppv[j];
                float rr  = (pw == 1.0f) ? ay : exp2f(pw * __log2f(ay));
                r[j] = __builtin_copysignf(rr, raw) + bbv[j];
            }
            *(f32x4*)(orow + uc) = r;
        }
    }
}

extern "C" void kernel_launch(void* const* d_in, const int* in_sizes, int n_in,
                              void* d_out, int out_size, void* d_ws, size_t ws_size,
                              hipStream_t stream) {
    const float* inp = (const float*)d_in[0];
    const float* w   = (const float*)d_in[1];
    const float* b   = (const float*)d_in[2];
    const float* p   = (const float*)d_in[3];
    const float* q   = (const float*)d_in[4];
    float* out = (float*)d_out;

    unsigned short* wfrag = (unsigned short*)d_ws;            // 12*16*64*8 bf16 = 196608 B
    float* winv = (float*)((char*)d_ws + 196608);
    float* p2   = winv + 256;
    float* bc   = p2 + 256;

    prep_kernel<<<49, 256, 0, stream>>>(w, b, p, q, wfrag, winv, p2, bc);
    cossim_main<<<1024, 512, 0, stream>>>(inp, wfrag, winv, p2, bc, q, out,
                                          2, 0.5f);
}

// Round 12
// 72.371 us; speedup vs baseline: 1.2890x; 1.2890x over previous
//
#include <hip/hip_runtime.h>

typedef __attribute__((ext_vector_type(8))) short short8;
typedef __attribute__((ext_vector_type(4))) float f32x4;

#define T_DIM 4096
#define C_DIM 128
#define U_DIM 256
#define BM 64
#define NROWS 66    // BM + 2 halo rows
#define LDK 136     // padded LDS row stride (bf16 elems)

__device__ __forceinline__ unsigned short f2bf(float f) {
    unsigned int u = __float_as_uint(f);
    u += 0x7FFFu + ((u >> 16) & 1u);   // round-to-nearest-even
    return (unsigned short)(u >> 16);
}

// Pre-pack w into MFMA fragment order: wfrag[ks][nt][lane][8] bf16,
// where k = ks*32 + (lane>>4)*8 + j, u = nt*16 + (lane&15).
__global__ void prep_kernel(const float* __restrict__ w,
                            const float* __restrict__ b,
                            const float* __restrict__ p,
                            const float* __restrict__ q,
                            unsigned short* __restrict__ wfrag,
                            float* __restrict__ winv,
                            float* __restrict__ p2,
                            float* __restrict__ bc) {
    if (blockIdx.x < 48) {
        int idx = blockIdx.x * 256 + threadIdx.x;   // 0..12287 lane-frags
        int l  = idx & 63;
        int nt = (idx >> 6) & 15;
        int ks = idx >> 10;                         // 0..11
        int n  = nt * 16 + (l & 15);
        int k0 = ks * 32 + ((l >> 4) << 3);
        #pragma unroll
        for (int j = 0; j < 8; ++j) {
            wfrag[(size_t)idx * 8 + j] = f2bf(w[(k0 + j) * U_DIM + n]);
        }
    } else {
        int u = threadIdx.x;                        // 0..255
        float ss = 0.f;
        for (int k = 0; k < 3 * C_DIM; ++k) {
            float v = w[k * U_DIM + u];
            ss += v * v;
        }
        float q2 = q[0] * q[0];
        winv[u] = 1.0f / (sqrtf(fmaxf(ss, 1e-12f)) + q2);
        float pv = p[u];
        p2[u] = pv * pv;
        bc[u] = b[u];
    }
}

// Load ks-step fragments: 4 ds_read_b128 (x) + 4 global dwordx4 (w, L2-hot)
#define KLOAD(ks, xv, wv)                                                  \
    do {                                                                   \
        const int tap_ = (ks) >> 2;                                        \
        const int c0_  = ((ks) & 3) * 32 + lg * 8;                         \
        _Pragma("unroll")                                                  \
        for (int tf = 0; tf < 4; ++tf)                                     \
            xv[tf] = *(const short8*)(&inp_s[tf * 16 + l15 + tap_][c0_]);  \
        _Pragma("unroll")                                                  \
        for (int uf = 0; uf < 4; ++uf)                                     \
            wv[uf] = wf[(size_t)((ks) * 16 + uw * 4 + uf) * 64 + l];       \
    } while (0)

#define KMFMA(xv, wv)                                                      \
    do {                                                                   \
        _Pragma("unroll")                                                  \
        for (int tf = 0; tf < 4; ++tf)                                     \
            _Pragma("unroll")                                              \
            for (int uf = 0; uf < 4; ++uf)                                 \
                acc[tf][uf] = __builtin_amdgcn_mfma_f32_16x16x32_bf16(     \
                    wv[uf], xv[tf], acc[tf][uf], 0, 0, 0);                 \
    } while (0)

__global__ __launch_bounds__(256, 3) void cossim_main(
        const float* __restrict__ inp,
        const unsigned short* __restrict__ wfrag,
        const float* __restrict__ winv,
        const float* __restrict__ p2g,
        const float* __restrict__ bg,
        const float* __restrict__ qg,
        float* __restrict__ out) {
    __shared__ unsigned short inp_s[NROWS][LDK];   // 17.9 KB
    __shared__ float ss_s[NROWS];
    __shared__ float xninv_s[BM];

    const int tid  = threadIdx.x;
    const int bidx = blockIdx.x;
    const int bb   = bidx >> 6;          // batch index (64 tiles per batch)
    const int t0   = (bidx & 63) * BM;   // tile start within batch

    // ---- Stage 66 input rows (t0-1 .. t0+64) as bf16; f32 sumsq per row ----
    {
        const int r0 = tid >> 5;         // 0..7
        const int lc = (tid & 31) * 4;   // float column
        float4 v[9];
        #pragma unroll
        for (int i = 0; i < 9; ++i) {
            int r = r0 + i * 8;
            int t = t0 + r - 1;
            float4 val = make_float4(0.f, 0.f, 0.f, 0.f);
            if (r < NROWS && t >= 0 && t < T_DIM) {
                val = *(const float4*)(inp + ((size_t)bb * T_DIM + t) * C_DIM + lc);
            }
            v[i] = val;
        }
        #pragma unroll
        for (int i = 0; i < 9; ++i) {
            int r = r0 + i * 8;
            if (r < NROWS) {
                float4 val = v[i];
                float part = val.x * val.x + val.y * val.y + val.z * val.z + val.w * val.w;
                #pragma unroll
                for (int o = 16; o > 0; o >>= 1) part += __shfl_xor(part, o, 32);
                if ((tid & 31) == 0) ss_s[r] = part;
                ushort4 sv;
                sv.x = f2bf(val.x); sv.y = f2bf(val.y);
                sv.z = f2bf(val.z); sv.w = f2bf(val.w);
                *(ushort4*)(&inp_s[r][lc]) = sv;
            }
        }
    }
    __syncthreads();
    if (tid < BM) {
        float s3 = ss_s[tid] + ss_s[tid + 1] + ss_s[tid + 2];
        float q2 = qg[0] * qg[0];
        xninv_s[tid] = 1.0f / (sqrtf(fmaxf(s3, 1e-12f)) + q2);
    }
    __syncthreads();

    // ---- MFMA: 4 waves u-split; each wave 64(t) x 64(u) ----
    // A = w fragment (m -> u), B = x fragment (n -> t).
    // D[u][t]: C/D layout col = lane&15 -> t, row = (lane>>4)*4 + j -> u.
    const int uw  = tid >> 6;        // 0..3 (u 64-col quarter)
    const int l   = tid & 63;
    const int l15 = l & 15;
    const int lg  = l >> 4;          // 0..3

    f32x4 acc[4][4];                 // [tf][uf]
    #pragma unroll
    for (int tf = 0; tf < 4; ++tf)
        #pragma unroll
        for (int uf = 0; uf < 4; ++uf)
            acc[tf][uf] = (f32x4){0.f, 0.f, 0.f, 0.f};

    const short8* wf = (const short8*)wfrag;

    // ---- 1-deep software-pipelined K-loop (named A/B buffers, static idx) ----
    short8 xvA[4], wvA[4], xvB[4], wvB[4];
    KLOAD(0, xvA, wvA);
    #pragma unroll
    for (int ks = 0; ks < 12; ++ks) {
        if ((ks & 1) == 0) {
            if (ks < 11) KLOAD(ks + 1, xvB, wvB);   // prefetch next
            KMFMA(xvA, wvA);                        // compute current
        } else {
            if (ks < 11) KLOAD(ks + 1, xvA, wvA);
            KMFMA(xvB, wvB);
        }
    }

    // ---- Epilogue: compact (no libm powf) ----
    #pragma unroll
    for (int tf = 0; tf < 4; ++tf) {
        int trow = tf * 16 + l15;
        float xi = xninv_s[trow];
        float* orow = out + ((size_t)bb * T_DIM + t0 + trow) * U_DIM;
        #pragma unroll
        for (int uf = 0; uf < 4; ++uf) {
            int uc = uw * 64 + uf * 16 + lg * 4;
            f32x4 wiv = *(const f32x4*)(winv + uc);
            f32x4 ppv = *(const f32x4*)(p2g + uc);
            f32x4 bbv = *(const f32x4*)(bg + uc);
            f32x4 r;
            #pragma unroll
            for (int j = 0; j < 4; ++j) {
                float raw = acc[tf][uf][j];
                float y   = raw * xi * wiv[j];
                float ay  = fabsf(y) + 1e-12f;
                float pw  = ppv[j];
                float rr  = (pw == 1.0f) ? ay : exp2f(pw * __log2f(ay));
                r[j] = __builtin_copysignf(rr, raw) + bbv[j];
            }
            *(f32x4*)(orow + uc) = r;
        }
    }
}

extern "C" void kernel_launch(void* const* d_in, const int* in_sizes, int n_in,
                              void* d_out, int out_size, void* d_ws, size_t ws_size,
                              hipStream_t stream) {
    const float* inp = (const float*)d_in[0];
    const float* w   = (const float*)d_in[1];
    const float* b   = (const float*)d_in[2];
    const float* p   = (const float*)d_in[3];
    const float* q   = (const float*)d_in[4];
    float* out = (float*)d_out;

    unsigned short* wfrag = (unsigned short*)d_ws;            // 12*16*64*8 bf16 = 196608 B
    float* winv = (float*)((char*)d_ws + 196608);
    float* p2   = winv + 256;
    float* bc   = p2 + 256;

    prep_kernel<<<49, 256, 0, stream>>>(w, b, p, q, wfrag, winv, p2, bc);
    cossim_main<<<2048, 256, 0, stream>>>(inp, wfrag, winv, p2, bc, q, out);
}